// Round 9
// baseline (280.062 us; speedup 1.0000x reference)
//
#include <hip/hip_runtime.h>

// MatchNet: MLP -> batched PDHG LP solve. B=2048 rows; m=128; n=512; 60 iters.
// Solve: 1024 blocks x 512 thr, 2 batch rows/block. 3 phases / 3 barriers:
//   P1 row gather of xb (float2/nnz, quad-split, per-lane guards) -> lam1
//   P2 col gather of lam1 -> u; wave-reduce ||u||^2 -> per-wave slots
//   P3 read slots -> sc; x,xb,l2 update; publish xb (b64)
// Index lists live pre-unpacked (u32 byte-offsets) in registers.
// Prep: 4-block coalesced scan (col masks + transposed row bitmasks), then
// 1-block finish: list build (sorted by construction) + 31-iter power iter.

#define NC    128
#define NS    512
#define BATCH 2048
#define HID   20

typedef unsigned int  uint;
typedef unsigned short ushort;
typedef float v2f __attribute__((ext_vector_type(2)));

// ---------------- workspace layout (bytes) ----------------
// 0     : float tau
// 64    : u32 colmask[512*4]    (8192)   bit i of word g = S[32g+i][col]
// 8256  : u32 rowbits[128*16]   (8192)   bit c of word w = S[row][32w+c]
// 16448 : u32 col_meta[512*16]  (32768)  byte-offs (*8) into lam1_lds, pad->128*8
// 49216 : u32 col_cnt[512]      (2048)   even, <=16
// 51264 : u32 row_meta[512*12]  (24576)  per (row,quad): byte-offs (*8), pad->512*8
// 75840 : u32 row_cnt[512]      (2048)   even, <=10

template <int CTRL, int RMASK = 0xf>
__device__ __forceinline__ float dppadd(float s) {
    return s + __builtin_bit_cast(float,
        __builtin_amdgcn_update_dpp(0, __builtin_bit_cast(int, s), CTRL, RMASK, 0xf, true));
}
__device__ __forceinline__ float quad_sum(float s) {   // total in all 4 lanes of quad
    s = dppadd<0xB1>(s);   // quad_perm [1,0,3,2]
    s = dppadd<0x4E>(s);   // quad_perm [2,3,0,1]
    return s;
}
__device__ __forceinline__ float wave_sum_bcast(float x) {
    float s = x;
    s = dppadd<0x111>(s);  // row_shr:1
    s = dppadd<0x112>(s);  // row_shr:2
    s = dppadd<0x114>(s);  // row_shr:4
    s = dppadd<0x118>(s);  // row_shr:8
    s = dppadd<0x142, 0xa>(s);  // row_bcast:15
    s = dppadd<0x143, 0xc>(s);  // row_bcast:31
    return __builtin_bit_cast(float, __builtin_amdgcn_readlane(__builtin_bit_cast(int, s), 63));
}
__device__ __forceinline__ v2f vfma(v2f a, v2f b, v2f c) { return __builtin_elementwise_fma(a, b, c); }
__device__ __forceinline__ v2f vmax0(v2f a) { const v2f z = {0.f, 0.f}; return __builtin_elementwise_max(a, z); }
__device__ __forceinline__ v2f vmin0(v2f a) { const v2f z = {0.f, 0.f}; return __builtin_elementwise_min(a, z); }

// ---- prep 1: block g scans rows [32g,32g+32) x all 512 cols (coalesced) ----
__global__ __launch_bounds__(512) void prep_scan(
    const float* __restrict__ S, uint* __restrict__ colmask_g, uint* __restrict__ rowbits_g)
{
    __shared__ uint mcol[NS];
    const int t = threadIdx.x, g = blockIdx.x;
    float vals[32];
#pragma unroll
    for (int j = 0; j < 32; ++j) vals[j] = S[(g * 32 + j) * NS + t];
    uint m = 0;
#pragma unroll
    for (int j = 0; j < 32; ++j) if (vals[j] != 0.0f) m |= (1u << j);
    mcol[t] = m;
    colmask_g[t * 4 + g] = m;
    __syncthreads();
    const int j = t >> 4, w = t & 15;                  // 32 rows x 16 words
    uint val = 0;
#pragma unroll
    for (int c = 0; c < 32; ++c)
        val |= (((mcol[w * 32 + c] >> j) & 1u) << c);
    rowbits_g[(g * 32 + j) * 16 + w] = val;
}

// ---- prep 2: build lists + power iteration for tau ----
__global__ __launch_bounds__(512) void prep_finish(
    const uint* __restrict__ colmask_g, const uint* __restrict__ rowbits_g,
    float* __restrict__ tau_ws,
    uint* __restrict__ col_meta, uint* __restrict__ col_cnt_g,
    uint* __restrict__ row_meta, uint* __restrict__ row_cnt_g)
{
    __shared__ ushort clist[NS][16];
    __shared__ ushort rql[NS][10];
    __shared__ int    ccnt_l[NS];
    __shared__ int    rcnt_l[NS];
    __shared__ float  u_lds[NS + 1];
    __shared__ float  sv_lds[NC];
    __shared__ float  red_pi[32];
    const int t = threadIdx.x;

    uint cm[4];
    { const uint4 c4 = *(const uint4*)&colmask_g[t * 4];
      cm[0] = c4.x; cm[1] = c4.y; cm[2] = c4.z; cm[3] = c4.w; }
    // col list (ascending rows), byte-addrs *8 into lam1_lds; pad -> 128*8
    {
        int cc = 0;
#pragma unroll
        for (int g = 0; g < 4; ++g) {
            uint m = cm[g];
            while (m) {
                const int b = __ffs(m) - 1; m &= m - 1;
                if (cc < 16) clist[t][cc] = (ushort)((g * 32 + b) * 8);
                ++cc;
            }
        }
        if (cc > 16) cc = 16;
        const int cc2 = (cc + 1) & ~1;
        for (int k = cc; k < 16; ++k) clist[t][k] = (ushort)(NC * 8);
        ccnt_l[t] = cc2;
    }
    // row quarter lists (entry e -> quarter e&3), byte-addrs *8 into xb_lds
    if (t < NC) {
#pragma unroll
        for (int q = 0; q < 4; ++q)
            for (int p = 0; p < 10; ++p) rql[t * 4 + q][p] = (ushort)(NS * 8);
        uint rb[16];
        { const uint4 a = *(const uint4*)&rowbits_g[t * 16];
          const uint4 b = *(const uint4*)&rowbits_g[t * 16 + 4];
          const uint4 c = *(const uint4*)&rowbits_g[t * 16 + 8];
          const uint4 d = *(const uint4*)&rowbits_g[t * 16 + 12];
          rb[0]=a.x; rb[1]=a.y; rb[2]=a.z;  rb[3]=a.w;  rb[4]=b.x;  rb[5]=b.y;  rb[6]=b.z;  rb[7]=b.w;
          rb[8]=c.x; rb[9]=c.y; rb[10]=c.z; rb[11]=c.w; rb[12]=d.x; rb[13]=d.y; rb[14]=d.z; rb[15]=d.w; }
        int e = 0;
#pragma unroll
        for (int w = 0; w < 16; ++w) {
            uint m = rb[w];
            while (m) {
                const int b = __ffs(m) - 1; m &= m - 1;
                const int q = e & 3, p = e >> 2;
                if (p < 10) rql[t * 4 + q][p] = (ushort)((w * 32 + b) * 8);
                ++e;
            }
        }
#pragma unroll
        for (int q = 0; q < 4; ++q) {
            int n = (e - q + 3) >> 2;
            if (n < 0) n = 0;
            if (n > 10) n = 10;
            rcnt_l[t * 4 + q] = (n + 1) & ~1;
        }
    }
    if (t == 0) u_lds[NS] = 0.0f;
    if (t < 32) red_pi[t] = 0.0f;
    u_lds[t] = 1.0f;
    __syncthreads();

    // export (u32 unpacked byte-offsets)
    {
        col_cnt_g[t] = (uint)ccnt_l[t];
#pragma unroll
        for (int k = 0; k < 16; ++k) col_meta[t * 16 + k] = (uint)clist[t][k];
        row_cnt_g[t] = (uint)rcnt_l[t];
#pragma unroll
        for (int k = 0; k < 12; ++k)
            row_meta[t * 12 + k] = (k < 10) ? (uint)rql[t][k] : (uint)(NS * 8);
    }

    // power iteration: 31 iters, quad-split rows, 2 barriers/iter
    const int rcn = rcnt_l[t];
    float u_loc = 1.0f;
    for (int it = 0; it <= 30; ++it) {
        const float inv = it ? rsqrtf(red_pi[it - 1]) : 1.0f;
        float s = 0.0f;
        for (int k = 0; k < rcn; ++k) {
            const uint a = rql[t][k];
            s += *(const float*)((const char*)u_lds + (a >> 1));   // *8 -> *4
        }
        s = quad_sum(s * inv);
        if ((t & 3) == 3) sv_lds[t >> 2] = s;
        __syncthreads();
        const float vt = u_loc * inv;
        float w = vt;
#pragma unroll
        for (int g = 0; g < 4; ++g) {
            uint m = cm[g];
            while (m) { const int b = __ffs(m) - 1; m &= m - 1; w += sv_lds[g * 32 + b]; }
        }
        float p = (it < 30) ? w * w : w * vt;
        p = wave_sum_bcast(p);
        if ((t & 63) == 0) atomicAdd(&red_pi[it], p);
        u_lds[t] = w;
        u_loc = w;
        __syncthreads();
    }
    if (t == 0) tau_ws[0] = 0.9f / sqrtf(red_pi[30]);
}

// ---- main solve ----
__global__ __launch_bounds__(512, 8) void solve_kernel(
    const float* __restrict__ X,
    const float* __restrict__ W1, const float* __restrict__ b1,
    const float* __restrict__ W2, const float* __restrict__ b2,
    const float* __restrict__ W3, const float* __restrict__ b3,
    const float* __restrict__ W4, const float* __restrict__ b4,
    const float* __restrict__ tau_ws,
    const uint* __restrict__ col_meta, const uint* __restrict__ col_cnt_g,
    const uint* __restrict__ row_meta, const uint* __restrict__ row_cnt_g,
    float* __restrict__ out)
{
    __shared__ alignas(16) float2 xb_lds[NS + 1];     // xb for both batch rows
    __shared__ alignas(16) float2 lam1_lds[NC + 1];
    __shared__ alignas(16) float2 redslot[8];         // per-wave ||u||^2 partials
    __shared__ alignas(16) float2 b_lds[NC];
    __shared__ float ha[2][HID], hb[2][HID];

    const int t  = threadIdx.x;
    const int r0 = blockIdx.x * 2, r1 = r0 + 1;

    // lists -> registers, pre-unpacked u32 byte offsets
    uint4 cA, cB, cC, cD, rA, rB, rC;
    { const uint4* g = (const uint4*)&col_meta[t * 16];
      cA = g[0]; cB = g[1]; cC = g[2]; cD = g[3]; }
    { const uint4* g = (const uint4*)&row_meta[t * 12];
      rA = g[0]; rB = g[1]; rC = g[2]; }
    const int ccn = (int)col_cnt_g[t];
    const int rcn = (int)row_cnt_g[t];

    if (t == 0) { xb_lds[NS] = make_float2(0.f, 0.f); lam1_lds[NC] = make_float2(0.f, 0.f); }
    if (t < NC) b_lds[t] = make_float2(X[r0 * NC + t], X[r1 * NC + t]);
    __syncthreads();

    // MLP (two rows on threads 0..39)
    if (t < 2 * HID) {
        const int rr = t >= HID, tt = t - rr * HID;
        float s = b1[tt];
        for (int k = 0; k < NC; ++k)
            s = fmaf(rr ? b_lds[k].y : b_lds[k].x, W1[k * HID + tt], s);
        ha[rr][tt] = tanhf(s);
    }
    __syncthreads();
    if (t < 2 * HID) {
        const int rr = t >= HID, tt = t - rr * HID;
        float s = b2[tt];
        for (int k = 0; k < HID; ++k) s = fmaf(ha[rr][k], W2[k * HID + tt], s);
        hb[rr][tt] = tanhf(s);
    }
    __syncthreads();
    if (t < 2 * HID) {
        const int rr = t >= HID, tt = t - rr * HID;
        float s = b3[tt];
        for (int k = 0; k < HID; ++k) s = fmaf(hb[rr][k], W3[k * HID + tt], s);
        ha[rr][tt] = tanhf(s);
    }
    __syncthreads();
    float z0 = b4[t], z1 = z0;
    for (int h = 0; h < HID; ++h) {
        const float w = W4[h * NS + t];
        z0 = fmaf(ha[0][h], w, z0);
        z1 = fmaf(ha[1][h], w, z1);
    }

    const float tau = tau_ws[0];
    const float c10 = 10.0f * tau;
    const v2f tauv = {tau, tau};
    const v2f sigv = tauv;
    const int r = t >> 2, q = t & 3;
    const v2f bb = {b_lds[r].x, b_lds[r].y};

    const v2f z = {z0, z1};
    v2f x  = vmax0(z);
    v2f xb = x;
    v2f u  = {0.f, 0.f};
    v2f l1 = {0.f, 0.f};
    v2f l2 = vmin0(sigv * xb);          // lam2_0 (uses xb_0 = x_0)
    xb_lds[t] = make_float2(xb.x, xb.y);
    __syncthreads();

    const char* xbB = (const char*)xb_lds;
    const char* lmB = (const char*)lam1_lds;
    for (int it = 0; it < 60; ++it) {
        // --- P1: row gather of xb (quad-split, per-lane guards) -> lam1 ---
        v2f s = {0.f, 0.f};
        s += *(const v2f*)(xbB + rA.x);
        s += *(const v2f*)(xbB + rA.y);
        if (rcn > 2) {
            s += *(const v2f*)(xbB + rA.z);
            s += *(const v2f*)(xbB + rA.w);
            if (rcn > 4) {
                s += *(const v2f*)(xbB + rB.x);
                s += *(const v2f*)(xbB + rB.y);
                if (rcn > 6) {
                    s += *(const v2f*)(xbB + rB.z);
                    s += *(const v2f*)(xbB + rB.w);
                    if (rcn > 8) {
                        s += *(const v2f*)(xbB + rC.x);
                        s += *(const v2f*)(xbB + rC.y);
                    }
                }
            }
        }
        const v2f sq = {quad_sum(s.x), quad_sum(s.y)};
        l1 = vmax0(vfma(sigv, sq - bb, l1));
        if (q == 3) lam1_lds[r] = make_float2(l1.x, l1.y);
        __syncthreads();                                  // B1: lam1 ready
        // --- P2: col gather -> u; norm partials ---
        v2f s2 = {0.f, 0.f};
        s2 += *(const v2f*)(lmB + cA.x);
        s2 += *(const v2f*)(lmB + cA.y);
        if (ccn > 2) {
            s2 += *(const v2f*)(lmB + cA.z);
            s2 += *(const v2f*)(lmB + cA.w);
            if (ccn > 4) {
                s2 += *(const v2f*)(lmB + cB.x);
                s2 += *(const v2f*)(lmB + cB.y);
                if (ccn > 6) {
                    s2 += *(const v2f*)(lmB + cB.z);
                    s2 += *(const v2f*)(lmB + cB.w);
                    if (ccn > 8) {
                        s2 += *(const v2f*)(lmB + cC.x);
                        s2 += *(const v2f*)(lmB + cC.y);
                        if (ccn > 10) {
                            s2 += *(const v2f*)(lmB + cC.z);
                            s2 += *(const v2f*)(lmB + cC.w);
                            if (ccn > 12) {
                                s2 += *(const v2f*)(lmB + cD.x);
                                s2 += *(const v2f*)(lmB + cD.y);
                                if (ccn > 14) {
                                    s2 += *(const v2f*)(lmB + cD.z);
                                    s2 += *(const v2f*)(lmB + cD.w);
                                }
                            }
                        }
                    }
                }
            }
        }
        const v2f v = x - tauv * (s2 + l2);
        u = (v + tauv) - z;
        const v2f p = u * u;
        const float p0 = wave_sum_bcast(p.x);
        const float p1 = wave_sum_bcast(p.y);
        if ((t & 63) == 0) redslot[t >> 6] = make_float2(p0, p1);
        __syncthreads();                                  // B2: slots ready
        // --- P3: finish primal update; publish xb ---
        const float4* rs = (const float4*)redslot;
        const float4 Ra = rs[0], Rb = rs[1], Rc = rs[2], Rd = rs[3];
        const v2f tot = (((v2f){Ra.x, Ra.y} + (v2f){Ra.z, Ra.w}) +
                         ((v2f){Rb.x, Rb.y} + (v2f){Rb.z, Rb.w})) +
                        (((v2f){Rc.x, Rc.y} + (v2f){Rc.z, Rc.w}) +
                         ((v2f){Rd.x, Rd.y} + (v2f){Rd.z, Rd.w}));
        const v2f sc = {fmaxf(0.f, 1.f - c10 * rsqrtf(tot.x)),
                        fmaxf(0.f, 1.f - c10 * rsqrtf(tot.y))};
        const v2f xn = vfma(sc, u, z);
        xb = (xn + xn) - x;
        x  = xn;
        l2 = vmin0(vfma(sigv, xb, l2));
        xb_lds[t] = make_float2(xb.x, xb.y);
        __syncthreads();                                  // B3: xb ready
    }
    out[r0 * NS + t] = x.x;
    out[r1 * NS + t] = x.y;
}

extern "C" void kernel_launch(void* const* d_in, const int* in_sizes, int n_in,
                              void* d_out, int out_size, void* d_ws, size_t ws_size,
                              hipStream_t stream)
{
    const float* X  = (const float*)d_in[0];
    const float* W1 = (const float*)d_in[1];
    const float* b1 = (const float*)d_in[2];
    const float* W2 = (const float*)d_in[3];
    const float* b2 = (const float*)d_in[4];
    const float* W3 = (const float*)d_in[5];
    const float* b3 = (const float*)d_in[6];
    const float* W4 = (const float*)d_in[7];
    const float* b4 = (const float*)d_in[8];
    const float* S  = (const float*)d_in[9];
    float* out = (float*)d_out;

    char* ws = (char*)d_ws;
    float* tau_ws    = (float*)(ws + 0);
    uint*  colmask_g = (uint*)(ws + 64);
    uint*  rowbits_g = (uint*)(ws + 8256);
    uint*  col_meta  = (uint*)(ws + 16448);
    uint*  col_cnt_g = (uint*)(ws + 49216);
    uint*  row_meta  = (uint*)(ws + 51264);
    uint*  row_cnt_g = (uint*)(ws + 75840);

    prep_scan<<<4, 512, 0, stream>>>(S, colmask_g, rowbits_g);
    prep_finish<<<1, 512, 0, stream>>>(colmask_g, rowbits_g, tau_ws,
                                       col_meta, col_cnt_g, row_meta, row_cnt_g);
    solve_kernel<<<BATCH / 2, 512, 0, stream>>>(X, W1, b1, W2, b2, W3, b3, W4, b4,
                                                tau_ws, col_meta, col_cnt_g,
                                                row_meta, row_cnt_g, out);
}

// Round 10
// 269.795 us; speedup vs baseline: 1.0381x; 1.0381x over previous
//
#include <hip/hip_runtime.h>

// MatchNet: MLP -> batched PDHG LP solve. B=2048 rows; m=128; n=512; 60 iters.
// Solve: 512 blocks x 512 thr, 4 batch rows/block (v4f packed state, b128 LDS).
// 3 phases / 3 barriers per iter:
//   P1 row gather of xb (b128/nnz, quad-split, per-lane guards) -> lam1
//   P2 col gather of lam1 -> u; wave-reduce ||u||^2 (DPP) -> per-wave slots
//   P3 read slots -> sc; x,xb,l2 update; publish xb (b128)
// LDS arrays bank-padded: index j -> j + (j>>3) (16B stripes rotate banks).
// Index lists pre-unpacked (u32 byte-offsets, pad baked in) in registers.
// Prep: 4-block coalesced scan (col masks + transposed row bitmasks), then
// 1-block finish: list build (sorted by construction) + 31-iter power iter.

#define NC    128
#define NS    512
#define BATCH 2048
#define HID   20

typedef unsigned int  uint;
typedef unsigned short ushort;
typedef float v4f __attribute__((ext_vector_type(4)));

// ---------------- workspace layout (bytes) ----------------
// 0     : float tau
// 64    : u32 colmask[512*4]    (8192)   bit i of word g = S[32g+i][col]
// 8256  : u32 rowbits[128*16]   (8192)   bit c of word w = S[row][32w+c]
// 16448 : u32 col_meta[512*16]  (32768)  byte-offs (pi*16) into lam1_lds, dummy 2304
// 49216 : u32 col_cnt[512]      (2048)   even, <=16
// 51264 : u32 row_meta[512*12]  (24576)  per (row,quad): byte-offs (pj*16), dummy 9216
// 75840 : u32 row_cnt[512]      (2048)   even, <=10

template <int CTRL, int RMASK = 0xf>
__device__ __forceinline__ float dppadd(float s) {
    return s + __builtin_bit_cast(float,
        __builtin_amdgcn_update_dpp(0, __builtin_bit_cast(int, s), CTRL, RMASK, 0xf, true));
}
__device__ __forceinline__ float quad_sum(float s) {   // total in all 4 lanes of quad
    s = dppadd<0xB1>(s);   // quad_perm [1,0,3,2]
    s = dppadd<0x4E>(s);   // quad_perm [2,3,0,1]
    return s;
}
__device__ __forceinline__ float wave_sum_bcast(float x) {
    float s = x;
    s = dppadd<0x111>(s);  // row_shr:1
    s = dppadd<0x112>(s);  // row_shr:2
    s = dppadd<0x114>(s);  // row_shr:4
    s = dppadd<0x118>(s);  // row_shr:8
    s = dppadd<0x142, 0xa>(s);  // row_bcast:15
    s = dppadd<0x143, 0xc>(s);  // row_bcast:31
    return __builtin_bit_cast(float, __builtin_amdgcn_readlane(__builtin_bit_cast(int, s), 63));
}
__device__ __forceinline__ v4f quad_sum4(v4f s) {
    return (v4f){quad_sum(s.x), quad_sum(s.y), quad_sum(s.z), quad_sum(s.w)};
}
__device__ __forceinline__ v4f vfma(v4f a, v4f b, v4f c) { return __builtin_elementwise_fma(a, b, c); }
__device__ __forceinline__ v4f vmax0(v4f a) { const v4f z = {0.f,0.f,0.f,0.f}; return __builtin_elementwise_max(a, z); }
__device__ __forceinline__ v4f vmin0(v4f a) { const v4f z = {0.f,0.f,0.f,0.f}; return __builtin_elementwise_min(a, z); }

// ---- prep 1: block g scans rows [32g,32g+32) x all 512 cols (coalesced) ----
__global__ __launch_bounds__(512) void prep_scan(
    const float* __restrict__ S, uint* __restrict__ colmask_g, uint* __restrict__ rowbits_g)
{
    __shared__ uint mcol[NS];
    const int t = threadIdx.x, g = blockIdx.x;
    float vals[32];
#pragma unroll
    for (int j = 0; j < 32; ++j) vals[j] = S[(g * 32 + j) * NS + t];
    uint m = 0;
#pragma unroll
    for (int j = 0; j < 32; ++j) if (vals[j] != 0.0f) m |= (1u << j);
    mcol[t] = m;
    colmask_g[t * 4 + g] = m;
    __syncthreads();
    const int j = t >> 4, w = t & 15;                  // 32 rows x 16 words
    uint val = 0;
#pragma unroll
    for (int c = 0; c < 32; ++c)
        val |= (((mcol[w * 32 + c] >> j) & 1u) << c);
    rowbits_g[(g * 32 + j) * 16 + w] = val;
}

// ---- prep 2: build lists + power iteration for tau ----
__global__ __launch_bounds__(512) void prep_finish(
    const uint* __restrict__ colmask_g, const uint* __restrict__ rowbits_g,
    float* __restrict__ tau_ws,
    uint* __restrict__ col_meta, uint* __restrict__ col_cnt_g,
    uint* __restrict__ row_meta, uint* __restrict__ row_cnt_g)
{
    __shared__ ushort clist[NS][16];
    __shared__ ushort rql[NS][10];
    __shared__ int    ccnt_l[NS];
    __shared__ int    rcnt_l[NS];
    __shared__ float  u_lds[577];        // bank-padded: idx j -> j + (j>>3); dummy 576
    __shared__ float  sv_lds[NC];
    __shared__ float  red_pi[32];
    const int t = threadIdx.x;

    uint cm[4];
    { const uint4 c4 = *(const uint4*)&colmask_g[t * 4];
      cm[0] = c4.x; cm[1] = c4.y; cm[2] = c4.z; cm[3] = c4.w; }
    // col list (ascending rows), byte-offs pi*16 into lam1_lds; dummy 144*16
    {
        int cc = 0;
#pragma unroll
        for (int g = 0; g < 4; ++g) {
            uint m = cm[g];
            while (m) {
                const int b = __ffs(m) - 1; m &= m - 1;
                const int i = g * 32 + b;
                if (cc < 16) clist[t][cc] = (ushort)((i + (i >> 3)) * 16);
                ++cc;
            }
        }
        if (cc > 16) cc = 16;
        const int cc2 = (cc + 1) & ~1;
        for (int k = cc; k < 16; ++k) clist[t][k] = (ushort)(144 * 16);
        ccnt_l[t] = cc2;
    }
    // row quarter lists (entry e -> quarter e&3), byte-offs pj*16 into xb_lds
    if (t < NC) {
#pragma unroll
        for (int q = 0; q < 4; ++q)
            for (int p = 0; p < 10; ++p) rql[t * 4 + q][p] = (ushort)(576 * 16);
        uint rb[16];
        { const uint4 a = *(const uint4*)&rowbits_g[t * 16];
          const uint4 b = *(const uint4*)&rowbits_g[t * 16 + 4];
          const uint4 c = *(const uint4*)&rowbits_g[t * 16 + 8];
          const uint4 d = *(const uint4*)&rowbits_g[t * 16 + 12];
          rb[0]=a.x; rb[1]=a.y; rb[2]=a.z;  rb[3]=a.w;  rb[4]=b.x;  rb[5]=b.y;  rb[6]=b.z;  rb[7]=b.w;
          rb[8]=c.x; rb[9]=c.y; rb[10]=c.z; rb[11]=c.w; rb[12]=d.x; rb[13]=d.y; rb[14]=d.z; rb[15]=d.w; }
        int e = 0;
#pragma unroll
        for (int w = 0; w < 16; ++w) {
            uint m = rb[w];
            while (m) {
                const int b = __ffs(m) - 1; m &= m - 1;
                const int q = e & 3, p = e >> 2;
                const int j = w * 32 + b;
                if (p < 10) rql[t * 4 + q][p] = (ushort)((j + (j >> 3)) * 16);
                ++e;
            }
        }
#pragma unroll
        for (int q = 0; q < 4; ++q) {
            int n = (e - q + 3) >> 2;
            if (n < 0) n = 0;
            if (n > 10) n = 10;
            rcnt_l[t * 4 + q] = (n + 1) & ~1;
        }
    }
    if (t == 0) u_lds[576] = 0.0f;
    if (t < 32) red_pi[t] = 0.0f;
    u_lds[t + (t >> 3)] = 1.0f;
    __syncthreads();

    // export (u32 byte-offsets, pad baked in)
    {
        col_cnt_g[t] = (uint)ccnt_l[t];
#pragma unroll
        for (int k = 0; k < 16; ++k) col_meta[t * 16 + k] = (uint)clist[t][k];
        row_cnt_g[t] = (uint)rcnt_l[t];
#pragma unroll
        for (int k = 0; k < 12; ++k)
            row_meta[t * 12 + k] = (k < 10) ? (uint)rql[t][k] : (uint)(576 * 16);
    }

    // power iteration: 31 iters, quad-split rows, 2 barriers/iter
    const int rcn = rcnt_l[t];
    float u_loc = 1.0f;
    for (int it = 0; it <= 30; ++it) {
        const float inv = it ? rsqrtf(red_pi[it - 1]) : 1.0f;
        float s = 0.0f;
        for (int k = 0; k < rcn; ++k) {
            const uint a = rql[t][k];
            s += *(const float*)((const char*)u_lds + (a >> 2));   // pj*16 -> pj*4
        }
        s = quad_sum(s * inv);
        if ((t & 3) == 3) sv_lds[t >> 2] = s;
        __syncthreads();
        const float vt = u_loc * inv;
        float w = vt;
#pragma unroll
        for (int g = 0; g < 4; ++g) {
            uint m = cm[g];
            while (m) { const int b = __ffs(m) - 1; m &= m - 1; w += sv_lds[g * 32 + b]; }
        }
        float p = (it < 30) ? w * w : w * vt;
        p = wave_sum_bcast(p);
        if ((t & 63) == 0) atomicAdd(&red_pi[it], p);
        u_lds[t + (t >> 3)] = w;
        u_loc = w;
        __syncthreads();
    }
    if (t == 0) tau_ws[0] = 0.9f / sqrtf(red_pi[30]);
}

// ---- main solve: 4 batch rows per block ----
__global__ __launch_bounds__(512, 4) void solve_kernel(
    const float* __restrict__ X,
    const float* __restrict__ W1, const float* __restrict__ b1,
    const float* __restrict__ W2, const float* __restrict__ b2,
    const float* __restrict__ W3, const float* __restrict__ b3,
    const float* __restrict__ W4, const float* __restrict__ b4,
    const float* __restrict__ tau_ws,
    const uint* __restrict__ col_meta, const uint* __restrict__ col_cnt_g,
    const uint* __restrict__ row_meta, const uint* __restrict__ row_cnt_g,
    float* __restrict__ out)
{
    __shared__ alignas(16) v4f xb_lds[577];           // bank-padded, dummy 576 = 0
    __shared__ alignas(16) v4f lam1_lds[145];         // bank-padded, dummy 144 = 0
    __shared__ alignas(16) v4f redslot[8];            // per-wave ||u||^2 partials
    __shared__ alignas(16) v4f b_lds[NC];
    __shared__ float ha[4][HID], hb[4][HID];

    const int t  = threadIdx.x;
    const int r0 = blockIdx.x * 4;

    // lists -> registers, pre-unpacked u32 byte offsets (pad baked in)
    uint4 cA, cB, cC, cD, rA, rB, rC;
    { const uint4* g = (const uint4*)&col_meta[t * 16];
      cA = g[0]; cB = g[1]; cC = g[2]; cD = g[3]; }
    { const uint4* g = (const uint4*)&row_meta[t * 12];
      rA = g[0]; rB = g[1]; rC = g[2]; }
    const int ccn = (int)col_cnt_g[t];
    const int rcn = (int)row_cnt_g[t];

    if (t == 0) {
        xb_lds[576]   = (v4f){0.f, 0.f, 0.f, 0.f};
        lam1_lds[144] = (v4f){0.f, 0.f, 0.f, 0.f};
    }
    if (t < NC)
        b_lds[t] = (v4f){X[r0 * NC + t],       X[(r0 + 1) * NC + t],
                         X[(r0 + 2) * NC + t], X[(r0 + 3) * NC + t]};
    __syncthreads();

    // MLP (four rows on threads 0..79)
    if (t < 4 * HID) {
        const int rr = t / HID, tt = t - rr * HID;
        float s = b1[tt];
        for (int k = 0; k < NC; ++k) s = fmaf(b_lds[k][rr], W1[k * HID + tt], s);
        ha[rr][tt] = tanhf(s);
    }
    __syncthreads();
    if (t < 4 * HID) {
        const int rr = t / HID, tt = t - rr * HID;
        float s = b2[tt];
        for (int k = 0; k < HID; ++k) s = fmaf(ha[rr][k], W2[k * HID + tt], s);
        hb[rr][tt] = tanhf(s);
    }
    __syncthreads();
    if (t < 4 * HID) {
        const int rr = t / HID, tt = t - rr * HID;
        float s = b3[tt];
        for (int k = 0; k < HID; ++k) s = fmaf(hb[rr][k], W3[k * HID + tt], s);
        ha[rr][tt] = tanhf(s);
    }
    __syncthreads();
    v4f z;
    {
        const float bz = b4[t];
        z = (v4f){bz, bz, bz, bz};
        for (int h = 0; h < HID; ++h) {
            const float w = W4[h * NS + t];
            const v4f hv = {ha[0][h], ha[1][h], ha[2][h], ha[3][h]};
            z = vfma(hv, (v4f){w, w, w, w}, z);
        }
    }

    const float tau = tau_ws[0];
    const float c10 = 10.0f * tau;
    const v4f tauv = {tau, tau, tau, tau};
    const v4f sigv = tauv;
    const int r = t >> 2, q = t & 3;
    const int pub = t + (t >> 3);            // padded publish index
    const int pir = r + (r >> 3);            // padded lam1 index
    const v4f bb = b_lds[r];

    v4f x  = vmax0(z);
    v4f xb = x;
    v4f u  = {0.f, 0.f, 0.f, 0.f};
    v4f l1 = {0.f, 0.f, 0.f, 0.f};
    v4f l2 = vmin0(sigv * xb);               // lam2_0 (uses xb_0 = x_0)
    xb_lds[pub] = xb;
    __syncthreads();

    const char* xbB = (const char*)xb_lds;
    const char* lmB = (const char*)lam1_lds;
    for (int it = 0; it < 60; ++it) {
        // --- P1: row gather of xb (quad-split, per-lane guards) -> lam1 ---
        v4f s = {0.f, 0.f, 0.f, 0.f};
        s += *(const v4f*)(xbB + rA.x);
        s += *(const v4f*)(xbB + rA.y);
        if (rcn > 2) {
            s += *(const v4f*)(xbB + rA.z);
            s += *(const v4f*)(xbB + rA.w);
            if (rcn > 4) {
                s += *(const v4f*)(xbB + rB.x);
                s += *(const v4f*)(xbB + rB.y);
                if (rcn > 6) {
                    s += *(const v4f*)(xbB + rB.z);
                    s += *(const v4f*)(xbB + rB.w);
                    if (rcn > 8) {
                        s += *(const v4f*)(xbB + rC.x);
                        s += *(const v4f*)(xbB + rC.y);
                    }
                }
            }
        }
        const v4f sq = quad_sum4(s);
        l1 = vmax0(vfma(sigv, sq - bb, l1));
        if (q == 3) lam1_lds[pir] = l1;
        __syncthreads();                                  // B1: lam1 ready
        // --- P2: col gather -> u; norm partials ---
        v4f s2 = {0.f, 0.f, 0.f, 0.f};
        s2 += *(const v4f*)(lmB + cA.x);
        s2 += *(const v4f*)(lmB + cA.y);
        if (ccn > 2) {
            s2 += *(const v4f*)(lmB + cA.z);
            s2 += *(const v4f*)(lmB + cA.w);
            if (ccn > 4) {
                s2 += *(const v4f*)(lmB + cB.x);
                s2 += *(const v4f*)(lmB + cB.y);
                if (ccn > 6) {
                    s2 += *(const v4f*)(lmB + cB.z);
                    s2 += *(const v4f*)(lmB + cB.w);
                    if (ccn > 8) {
                        s2 += *(const v4f*)(lmB + cC.x);
                        s2 += *(const v4f*)(lmB + cC.y);
                        if (ccn > 10) {
                            s2 += *(const v4f*)(lmB + cC.z);
                            s2 += *(const v4f*)(lmB + cC.w);
                            if (ccn > 12) {
                                s2 += *(const v4f*)(lmB + cD.x);
                                s2 += *(const v4f*)(lmB + cD.y);
                                if (ccn > 14) {
                                    s2 += *(const v4f*)(lmB + cD.z);
                                    s2 += *(const v4f*)(lmB + cD.w);
                                }
                            }
                        }
                    }
                }
            }
        }
        const v4f v = x - tauv * (s2 + l2);
        u = (v + tauv) - z;
        const v4f p = u * u;
        const v4f ps = {wave_sum_bcast(p.x), wave_sum_bcast(p.y),
                        wave_sum_bcast(p.z), wave_sum_bcast(p.w)};
        if ((t & 63) == 0) redslot[t >> 6] = ps;
        __syncthreads();                                  // B2: slots ready
        // --- P3: finish primal update; publish xb ---
        const v4f tot = ((redslot[0] + redslot[1]) + (redslot[2] + redslot[3])) +
                        ((redslot[4] + redslot[5]) + (redslot[6] + redslot[7]));
        const v4f sc = {fmaxf(0.f, 1.f - c10 * rsqrtf(tot.x)),
                        fmaxf(0.f, 1.f - c10 * rsqrtf(tot.y)),
                        fmaxf(0.f, 1.f - c10 * rsqrtf(tot.z)),
                        fmaxf(0.f, 1.f - c10 * rsqrtf(tot.w))};
        const v4f xn = vfma(sc, u, z);
        xb = (xn + xn) - x;
        x  = xn;
        l2 = vmin0(vfma(sigv, xb, l2));
        xb_lds[pub] = xb;
        __syncthreads();                                  // B3: xb ready
    }
    out[r0 * NS + t]       = x.x;
    out[(r0 + 1) * NS + t] = x.y;
    out[(r0 + 2) * NS + t] = x.z;
    out[(r0 + 3) * NS + t] = x.w;
}

extern "C" void kernel_launch(void* const* d_in, const int* in_sizes, int n_in,
                              void* d_out, int out_size, void* d_ws, size_t ws_size,
                              hipStream_t stream)
{
    const float* X  = (const float*)d_in[0];
    const float* W1 = (const float*)d_in[1];
    const float* b1 = (const float*)d_in[2];
    const float* W2 = (const float*)d_in[3];
    const float* b2 = (const float*)d_in[4];
    const float* W3 = (const float*)d_in[5];
    const float* b3 = (const float*)d_in[6];
    const float* W4 = (const float*)d_in[7];
    const float* b4 = (const float*)d_in[8];
    const float* S  = (const float*)d_in[9];
    float* out = (float*)d_out;

    char* ws = (char*)d_ws;
    float* tau_ws    = (float*)(ws + 0);
    uint*  colmask_g = (uint*)(ws + 64);
    uint*  rowbits_g = (uint*)(ws + 8256);
    uint*  col_meta  = (uint*)(ws + 16448);
    uint*  col_cnt_g = (uint*)(ws + 49216);
    uint*  row_meta  = (uint*)(ws + 51264);
    uint*  row_cnt_g = (uint*)(ws + 75840);

    prep_scan<<<4, 512, 0, stream>>>(S, colmask_g, rowbits_g);
    prep_finish<<<1, 512, 0, stream>>>(colmask_g, rowbits_g, tau_ws,
                                       col_meta, col_cnt_g, row_meta, row_cnt_g);
    solve_kernel<<<BATCH / 4, 512, 0, stream>>>(X, W1, b1, W2, b2, W3, b3, W4, b4,
                                                tau_ws, col_meta, col_cnt_g,
                                                row_meta, row_cnt_g, out);
}